// Round 1
// baseline (186.949 us; speedup 1.0000x reference)
//
#include <hip/hip_runtime.h>
#include <cstdint>

// MillionBucketPyramid: multi-scale hashed embedding lookup with
// sign-bit-conditioned long-range buckets.
// B=32, T=2048, BUCKETS=4e6, E=4, windows {1,2,4,8}, out = (B,T,16) fp32.

constexpr int TT = 2048;
constexpr int BB = 32;
constexpr uint32_t BUCKETS = 4000000u;

__device__ constexpr uint64_t PRIMES64[8] = {
    2654435761ull, 2246822519ull, 3266489917ull, 2028178513ull,
    1220703125ull, 1610612741ull,  805306457ull,  402653189ull};

extern "C" __global__ void __launch_bounds__(256)
pyramid_kernel(const int* __restrict__ tokens,
               const float* __restrict__ t0,
               const float* __restrict__ t1,
               const float* __restrict__ t2,
               const float* __restrict__ t3,
               const float* __restrict__ cw,
               float* __restrict__ out)
{
    __shared__ int   stok[264];   // 8 halo + 256 tokens
    __shared__ float scw[64];     // cond_w (8x8)

    const int tid          = threadIdx.x;
    const int blocksPerRow = TT / 256;                  // 8
    const int b            = blockIdx.x / blocksPerRow;
    const int tBase        = (blockIdx.x % blocksPerRow) * 256;
    const int* row         = tokens + (size_t)b * TT;

    for (int i = tid; i < 264; i += 256) {
        const int t = tBase - 8 + i;
        stok[i] = (t >= 0) ? row[t] : 0;   // pre-sequence pad = 0 (matches jnp.pad)
    }
    if (tid < 64) scw[tid] = cw[tid];
    __syncthreads();

    const int t = tBase + tid;

    // Cumulative XOR hash; keys for windows 1,2,4,8 are prefixes.
    // stok[tid + 7 - i] == tokens[b, t-1-i]
    uint64_t x = 0;
    x ^= (uint64_t)(uint32_t)stok[tid + 7] * PRIMES64[0];
    const uint32_t k0 = (uint32_t)(x % BUCKETS);
    x ^= (uint64_t)(uint32_t)stok[tid + 6] * PRIMES64[1];
    const uint32_t k1 = (uint32_t)(x % BUCKETS);
    x ^= (uint64_t)(uint32_t)stok[tid + 5] * PRIMES64[2];
    x ^= (uint64_t)(uint32_t)stok[tid + 4] * PRIMES64[3];
    const uint32_t k2h = (uint32_t)(x % BUCKETS);
    x ^= (uint64_t)(uint32_t)stok[tid + 3] * PRIMES64[4];
    x ^= (uint64_t)(uint32_t)stok[tid + 2] * PRIMES64[5];
    x ^= (uint64_t)(uint32_t)stok[tid + 1] * PRIMES64[6];
    x ^= (uint64_t)(uint32_t)stok[tid + 0] * PRIMES64[7];
    const uint32_t k3h = (uint32_t)(x % BUCKETS);

    // Short-table gathers (16 B each, aligned: E=4 floats)
    const float4 e0 = *(const float4*)(t0 + (size_t)k0 * 4);
    const float4 e1 = *(const float4*)(t1 + (size_t)k1 * 4);

    // cond_logits[o] = sum_d cat[d] * cond_w[o][d]; sign -> XOR of primes
    const float cat[8] = {e0.x, e0.y, e0.z, e0.w, e1.x, e1.y, e1.z, e1.w};
    uint32_t ck = 0;
#pragma unroll
    for (int o = 0; o < 8; ++o) {
        float acc = 0.f;
#pragma unroll
        for (int d = 0; d < 8; ++d) acc = fmaf(cat[d], scw[o * 8 + d], acc);
        if (acc > 0.f) ck ^= (uint32_t)PRIMES64[o];
    }

    const uint32_t kk2 = (k2h ^ ck) % BUCKETS;
    const uint32_t kk3 = (k3h ^ ck) % BUCKETS;
    const float4 e2 = *(const float4*)(t2 + (size_t)kk2 * 4);
    const float4 e3 = *(const float4*)(t3 + (size_t)kk3 * 4);

    float4* o4 = (float4*)(out + (size_t)(b * TT + t) * 16);
    o4[0] = e0; o4[1] = e1; o4[2] = e2; o4[3] = e3;
}

extern "C" void kernel_launch(void* const* d_in, const int* in_sizes, int n_in,
                              void* d_out, int out_size, void* d_ws, size_t ws_size,
                              hipStream_t stream)
{
    const int*   tokens = (const int*)d_in[0];
    const float* t0     = (const float*)d_in[1];
    const float* t1     = (const float*)d_in[2];
    const float* t2     = (const float*)d_in[3];
    const float* t3     = (const float*)d_in[4];
    const float* cw     = (const float*)d_in[5];
    float*       out    = (float*)d_out;

    const dim3 grid(BB * (TT / 256));   // 256 blocks
    pyramid_kernel<<<grid, 256, 0, stream>>>(tokens, t0, t1, t2, t3, cw, out);
}

// Round 2
// 186.209 us; speedup vs baseline: 1.0040x; 1.0040x over previous
//
#include <hip/hip_runtime.h>
#include <cstdint>

// MillionBucketPyramid: multi-scale hashed embedding lookup with
// sign-bit-conditioned long-range buckets.
// B=32, T=2048, BUCKETS=4e6, E=4, windows {1,2,4,8}, out = (B,T,16) fp32.
//
// Round-2 structure: 4 lanes per element (lane r owns table r) -> 4096 waves
// (4 waves/SIMD) instead of 1024 (1/SIMD), to hide the ~900-cy random-gather
// latency of the 2-deep dependent chain. Duplicate short-gather addresses in
// lanes 2/3 coalesce with lanes 0/1 (same cache line -> one transaction).

constexpr int TT = 2048;
constexpr int BB = 32;
constexpr uint32_t BUCKETS = 4000000u;
constexpr int ELEMS_PER_BLOCK = 64;              // 256 threads / 4 lanes-per-elem

__device__ constexpr uint64_t PRIMES64[8] = {
    2654435761ull, 2246822519ull, 3266489917ull, 2028178513ull,
    1220703125ull, 1610612741ull,  805306457ull,  402653189ull};

extern "C" __global__ void __launch_bounds__(256)
pyramid_kernel(const int* __restrict__ tokens,
               const float* __restrict__ t0,
               const float* __restrict__ t1,
               const float* __restrict__ t2,
               const float* __restrict__ t3,
               const float* __restrict__ cw,
               float* __restrict__ out)
{
    __shared__ int   stok[ELEMS_PER_BLOCK + 8];  // 8 halo + 64 tokens
    __shared__ float scw[64];                    // cond_w (8x8)

    const int tid = threadIdx.x;
    const int el  = tid >> 2;                    // element within block [0,64)
    const int r   = tid & 3;                     // table index for this lane

    const int blocksPerRow = TT / ELEMS_PER_BLOCK;        // 32
    const int b     = blockIdx.x / blocksPerRow;
    const int tBase = (blockIdx.x % blocksPerRow) * ELEMS_PER_BLOCK;
    const int* row  = tokens + (size_t)b * TT;

    if (tid < ELEMS_PER_BLOCK + 8) {
        const int t = tBase - 8 + tid;
        stok[tid] = (t >= 0) ? row[t] : 0;       // pre-sequence pad = 0
    }
    if (tid < 64) scw[tid] = cw[tid];
    __syncthreads();

    // Cumulative XOR hash; keys for windows 1,2,4,8 are prefixes.
    // stok[el + 7 - j] == tokens[b, t-1-j]
    uint64_t x = 0;
    x ^= (uint64_t)(uint32_t)stok[el + 7] * PRIMES64[0];
    const uint32_t k0 = (uint32_t)(x % BUCKETS);
    x ^= (uint64_t)(uint32_t)stok[el + 6] * PRIMES64[1];
    const uint32_t k1 = (uint32_t)(x % BUCKETS);
    x ^= (uint64_t)(uint32_t)stok[el + 5] * PRIMES64[2];
    x ^= (uint64_t)(uint32_t)stok[el + 4] * PRIMES64[3];
    const uint32_t k2h = (uint32_t)(x % BUCKETS);
    x ^= (uint64_t)(uint32_t)stok[el + 3] * PRIMES64[4];
    x ^= (uint64_t)(uint32_t)stok[el + 2] * PRIMES64[5];
    x ^= (uint64_t)(uint32_t)stok[el + 1] * PRIMES64[6];
    x ^= (uint64_t)(uint32_t)stok[el + 0] * PRIMES64[7];
    const uint32_t k3h = (uint32_t)(x % BUCKETS);

    // Round 1: lanes {0,2} load t0[k0], lanes {1,3} load t1[k1] (dups coalesce)
    const float*  sp = (r & 1) ? t1 : t0;
    const uint32_t sk = (r & 1) ? k1 : k0;
    const float4 v1 = *(const float4*)(sp + (size_t)sk * 4);

    // Broadcast e0 (group lane 0) and e1 (group lane 1) to all 4 lanes
    const int wl   = threadIdx.x & 63;
    const int base = wl & ~3;
    float cat[8];
    cat[0] = __shfl(v1.x, base + 0, 64);
    cat[1] = __shfl(v1.y, base + 0, 64);
    cat[2] = __shfl(v1.z, base + 0, 64);
    cat[3] = __shfl(v1.w, base + 0, 64);
    cat[4] = __shfl(v1.x, base + 1, 64);
    cat[5] = __shfl(v1.y, base + 1, 64);
    cat[6] = __shfl(v1.z, base + 1, 64);
    cat[7] = __shfl(v1.w, base + 1, 64);

    // cond_key: identical fmaf order to the reference-validated round-1 kernel
    uint32_t ck = 0;
#pragma unroll
    for (int o = 0; o < 8; ++o) {
        float acc = 0.f;
#pragma unroll
        for (int d = 0; d < 8; ++d) acc = fmaf(cat[d], scw[o * 8 + d], acc);
        if (acc > 0.f) ck ^= (uint32_t)PRIMES64[o];
    }

    // Round 2: lanes {0,2} load t2[kk2], lanes {1,3} load t3[kk3]
    const uint32_t kk2 = (k2h ^ ck) % BUCKETS;
    const uint32_t kk3 = (k3h ^ ck) % BUCKETS;
    const float*   lp  = (r & 1) ? t3 : t2;
    const uint32_t lk  = (r & 1) ? kk3 : kk2;
    const float4 v2 = *(const float4*)(lp + (size_t)lk * 4);

    // Lane r stores slot r: r<2 -> its own short gather, r>=2 -> its long gather
    const float4 vo = (r < 2) ? v1 : v2;
    const int elemG = b * TT + tBase + el;
    *(float4*)(out + (size_t)elemG * 16 + r * 4) = vo;
}

extern "C" void kernel_launch(void* const* d_in, const int* in_sizes, int n_in,
                              void* d_out, int out_size, void* d_ws, size_t ws_size,
                              hipStream_t stream)
{
    const int*   tokens = (const int*)d_in[0];
    const float* t0     = (const float*)d_in[1];
    const float* t1     = (const float*)d_in[2];
    const float* t2     = (const float*)d_in[3];
    const float* t3     = (const float*)d_in[4];
    const float* cw     = (const float*)d_in[5];
    float*       out    = (float*)d_out;

    const dim3 grid(BB * (TT / ELEMS_PER_BLOCK));   // 32*32 = 1024 blocks
    pyramid_kernel<<<grid, 256, 0, stream>>>(tokens, t0, t1, t2, t3, cw, out);
}